// Round 1
// baseline (13142.696 us; speedup 1.0000x reference)
//
#include <hip/hip_runtime.h>
#include <stdint.h>

#define TSTEPS 512

typedef __attribute__((ext_vector_type(8))) _Float16 half8;
typedef __attribute__((ext_vector_type(4))) _Float16 half4;
typedef __attribute__((ext_vector_type(4))) float f32x4;
typedef __attribute__((ext_vector_type(4))) float float4v;

static __device__ __forceinline__ float sigm(float x) { return 1.f / (1.f + __expf(-x)); }
static __device__ __forceinline__ float tanh_(float x) {
  x = fminf(15.f, fmaxf(-15.f, x));
  float e = __expf(-2.f * x);
  return (1.f - e) / (1.f + e);
}
static __device__ __forceinline__ half8 ld8(const _Float16* p) { return *(const half8*)p; }
static __device__ __forceinline__ f32x4 MFMA(half8 a, half8 b, f32x4 c) {
  return __builtin_amdgcn_mfma_f32_16x16x32_f16(a, b, c, 0, 0, 0);
}

// ---------------- f32 -> f16 conversion / init ----------------
__global__ __launch_bounds__(256) void kconv(
    const float* __restrict__ xs, const float* __restrict__ wih,
    const float* __restrict__ wxh, const float* __restrict__ whhf,
    const float* __restrict__ wrf, const float* __restrict__ h0,
    _Float16* __restrict__ xs_h, _Float16* __restrict__ wcat,
    _Float16* __restrict__ whh, _Float16* __restrict__ wr,
    _Float16* __restrict__ h_h) {
  const long n1 = 8388608;   // xs / 4
  const long n2 = 1048576;   // wcat / 4 (3072*1024 from W_ih then 1024*1024 from W_xh)
  const long n3 = 786432;    // whh / 4
  const long n4 = 262144;    // wr / 4
  const long n5 = 16384;     // h0 / 4
  const long total = n1 + n2 + n3 + n4 + n5;
  for (long i = (long)blockIdx.x * 256 + threadIdx.x; i < total; i += (long)gridDim.x * 256) {
    const float* s; _Float16* d;
    if (i < n1) { s = xs + i * 4; d = xs_h + i * 4; }
    else if (i < n1 + n2) {
      long e = (i - n1) * 4;
      s = (e < 3145728) ? (wih + e) : (wxh + (e - 3145728));
      d = wcat + e;
    } else if (i < n1 + n2 + n3) { long e = (i - n1 - n2) * 4; s = whhf + e; d = whh + e; }
    else if (i < n1 + n2 + n3 + n4) { long e = (i - n1 - n2 - n3) * 4; s = wrf + e; d = wr + e; }
    else { long e = (i - n1 - n2 - n3 - n4) * 4; s = h0 + e; d = h_h + e; }
    float4v v = *(const float4v*)s;
    half4 o = { (_Float16)v.x, (_Float16)v.y, (_Float16)v.z, (_Float16)v.w };
    *(half4*)d = o;
  }
}

// ---------------- big input-side GEMM: xgh[32768][4096] = xs @ [W_ih;W_xh]^T + bias ----------------
__global__ __launch_bounds__(256) void kgemm(
    const _Float16* __restrict__ X, const _Float16* __restrict__ W,
    const float* __restrict__ b_ih, const float* __restrict__ b_xh,
    _Float16* __restrict__ C) {
  __shared__ _Float16 As[128 * 40], Bs[128 * 40];  // pitch 40 halfs (80B) to spread banks
  const int tid = threadIdx.x;
  const int lane = tid & 63;
  const int w = tid >> 6;
  const int wm = (w >> 1) * 64, wn = (w & 1) * 64;
  const int bn = blockIdx.x * 128;
  const int bm = blockIdx.y * 128;
  const int arow = tid >> 2;
  const int kk8 = (tid & 3) * 8;
  const int fr = lane & 15, fq = lane >> 4;
  const f32x4 zero = {0.f, 0.f, 0.f, 0.f};
  f32x4 acc[4][4];
  #pragma unroll
  for (int a = 0; a < 4; a++)
    #pragma unroll
    for (int b = 0; b < 4; b++) acc[a][b] = zero;
  for (int kt = 0; kt < 1024; kt += 32) {
    __syncthreads();
    #pragma unroll
    for (int j = 0; j < 2; j++) {
      int r = j * 64 + arow;
      *(half8*)(As + r * 40 + kk8) = ld8(X + (size_t)(bm + r) * 1024 + kt + kk8);
      *(half8*)(Bs + r * 40 + kk8) = ld8(W + (size_t)(bn + r) * 1024 + kt + kk8);
    }
    __syncthreads();
    half8 af[4], bfr[4];
    #pragma unroll
    for (int i = 0; i < 4; i++) {
      af[i]  = *(const half8*)(As + (wm + i * 16 + fr) * 40 + fq * 8);
      bfr[i] = *(const half8*)(Bs + (wn + i * 16 + fr) * 40 + fq * 8);
    }
    #pragma unroll
    for (int mi = 0; mi < 4; mi++)
      #pragma unroll
      for (int ni = 0; ni < 4; ni++)
        acc[mi][ni] = MFMA(af[mi], bfr[ni], acc[mi][ni]);
  }
  #pragma unroll
  for (int mi = 0; mi < 4; mi++)
    #pragma unroll
    for (int ni = 0; ni < 4; ni++) {
      int col = bn + wn + ni * 16 + fr;
      float bias = (col < 3072) ? b_ih[col] : b_xh[col - 3072];
      #pragma unroll
      for (int r = 0; r < 4; r++) {
        int row = bm + wm + mi * 16 + fq * 4 + r;
        C[(size_t)row * 4096 + col] = (_Float16)(acc[mi][ni][r] + bias);
      }
    }
}

// ---------------- grid barrier (monotonic counter, agent scope) ----------------
__device__ __forceinline__ void gbar(unsigned* bar, unsigned target) {
  __syncthreads();
  if (threadIdx.x == 0) {
    __hip_atomic_fetch_add(bar, 1u, __ATOMIC_RELEASE, __HIP_MEMORY_SCOPE_AGENT);
    while (__hip_atomic_load(bar, __ATOMIC_ACQUIRE, __HIP_MEMORY_SCOPE_AGENT) < target)
      __builtin_amdgcn_s_sleep(1);
  }
  __syncthreads();
}

// ---------------- persistent recurrent kernel ----------------
// 64 wgs x 256 thr. wg g owns h-cols [16g,16g+16). Wave ki holds K-slice [256ki,256ki+256)
// of W_hh rows (r,z,e for its cols) + W_r rows in VGPRs. Split-K partials reduced in LDS.
__global__ __launch_bounds__(256, 1) void krec(
    const _Float16* __restrict__ xgh, const float* __restrict__ ms,
    const _Float16* __restrict__ whh, const _Float16* __restrict__ wr,
    const float* __restrict__ b_hh, const float* __restrict__ b_r,
    const float* __restrict__ h0,
    _Float16* __restrict__ h_h, _Float16* __restrict__ rh_h,
    float* __restrict__ out, unsigned* __restrict__ bar) {
  const int g = blockIdx.x;
  const int tid = threadIdx.x;
  const int lane = tid & 63;
  const int ki = tid >> 6;
  const int fr = lane & 15, fq = lane >> 4;
  const int cbase = g * 16;

  __shared__ float red[4 * 64 * 49];  // reused with pitch 49 (phase A) / 17 (phase B)

  // weight fragments -> registers (held across all 512 steps)
  half8 wfA[3][8], wfB[8];
  {
    const _Float16* ba = whh + (size_t)(cbase + fr) * 1024 + ki * 256 + fq * 8;
    #pragma unroll
    for (int nt = 0; nt < 3; nt++)
      #pragma unroll
      for (int ks = 0; ks < 8; ks++)
        wfA[nt][ks] = ld8(ba + (size_t)nt * 1048576 + ks * 32);
    const _Float16* bb = wr + (size_t)(cbase + fr) * 1024 + ki * 256 + fq * 8;
    #pragma unroll
    for (int ks = 0; ks < 8; ks++) wfB[ks] = ld8(bb + ks * 32);
  }

  // per-thread ownership for the elementwise math: c = tid&15, m = (tid>>4) + 16*i
  const int c = tid & 15;
  const int mb = tid >> 4;
  const int gc = cbase + c;
  const float bhr = b_hh[gc], bhz = b_hh[1024 + gc], bhe = b_hh[2048 + gc];
  const float brr = b_r[gc];
  float hreg[4];
  #pragma unroll
  for (int i = 0; i < 4; i++) hreg[i] = h0[(size_t)(mb + 16 * i) * 1024 + gc];

  const f32x4 zero = {0.f, 0.f, 0.f, 0.f};
  unsigned barcnt = 0;

  #pragma clang loop unroll(disable)
  for (int t = 0; t < TSTEPS; t++) {
    const _Float16* xg_t = xgh + (size_t)t * 262144;

    // ---- phase A: gates = sigmoid(xg + h @ Whh^T + b_hh); publish rh = r*h
    f32x4 accA[4][3];
    #pragma unroll
    for (int mt = 0; mt < 4; mt++)
      #pragma unroll
      for (int nt = 0; nt < 3; nt++) accA[mt][nt] = zero;
    {
      const _Float16* hb = h_h + fr * 1024 + ki * 256 + fq * 8;
      #pragma unroll
      for (int ks = 0; ks < 8; ks++) {
        half8 a[4];
        #pragma unroll
        for (int mt = 0; mt < 4; mt++) a[mt] = ld8(hb + mt * 16384 + ks * 32);
        #pragma unroll
        for (int mt = 0; mt < 4; mt++)
          #pragma unroll
          for (int nt = 0; nt < 3; nt++)
            accA[mt][nt] = MFMA(a[mt], wfA[nt][ks], accA[mt][nt]);
      }
    }
    #pragma unroll
    for (int mt = 0; mt < 4; mt++)
      #pragma unroll
      for (int nt = 0; nt < 3; nt++)
        #pragma unroll
        for (int r = 0; r < 4; r++)
          red[(ki * 64 + mt * 16 + fq * 4 + r) * 49 + nt * 16 + fr] = accA[mt][nt][r];
    __syncthreads();
    float zz[4], ee[4];
    #pragma unroll
    for (int i = 0; i < 4; i++) {
      const int m = mb + 16 * i;
      float sr = 0.f, sz = 0.f, se = 0.f;
      #pragma unroll
      for (int w = 0; w < 4; w++) {
        const float* p = red + (w * 64 + m) * 49;
        sr += p[c]; sz += p[16 + c]; se += p[32 + c];
      }
      float xr = (float)xg_t[(size_t)m * 4096 + gc];
      float xz = (float)xg_t[(size_t)m * 4096 + 1024 + gc];
      float xe = (float)xg_t[(size_t)m * 4096 + 2048 + gc];
      float rg = sigm(xr + sr + bhr);
      zz[i] = sigm(xz + sz + bhz);
      ee[i] = sigm(xe + se + bhe);
      rh_h[m * 1024 + gc] = (_Float16)(rg * hreg[i]);
    }
    barcnt++; gbar(bar, barcnt * 64u);

    // ---- phase B: ht_hat = tanh(xh + rh @ Wr^T + b_r); h = z*h + (1-z)*ht_hat + e*tanh(ms)
    f32x4 accB[4];
    #pragma unroll
    for (int mt = 0; mt < 4; mt++) accB[mt] = zero;
    {
      const _Float16* rb = rh_h + fr * 1024 + ki * 256 + fq * 8;
      #pragma unroll
      for (int ks = 0; ks < 8; ks++)
        #pragma unroll
        for (int mt = 0; mt < 4; mt++)
          accB[mt] = MFMA(ld8(rb + mt * 16384 + ks * 32), wfB[ks], accB[mt]);
    }
    #pragma unroll
    for (int mt = 0; mt < 4; mt++)
      #pragma unroll
      for (int r = 0; r < 4; r++)
        red[(ki * 64 + mt * 16 + fq * 4 + r) * 17 + fr] = accB[mt][r];
    __syncthreads();
    float* outT = out + (size_t)t * 65536;
    #pragma unroll
    for (int i = 0; i < 4; i++) {
      const int m = mb + 16 * i;
      float s = 0.f;
      #pragma unroll
      for (int w = 0; w < 4; w++) s += red[(w * 64 + m) * 17 + c];
      float xh = (float)xg_t[(size_t)m * 4096 + 3072 + gc];
      float hh = tanh_(xh + s + brr);
      float tmv = tanh_(ms[(size_t)t * 65536 + m * 1024 + gc]);
      float hn = zz[i] * hreg[i] + (1.f - zz[i]) * hh + ee[i] * tmv;
      hreg[i] = hn;
      __builtin_nontemporal_store(hn, outT + m * 1024 + gc);
      h_h[m * 1024 + gc] = (_Float16)hn;
    }
    barcnt++; gbar(bar, barcnt * 64u);
  }
  // h_last
  float* outL = out + (size_t)TSTEPS * 65536;
  #pragma unroll
  for (int i = 0; i < 4; i++) outL[(mb + 16 * i) * 1024 + gc] = hreg[i];
}

extern "C" void kernel_launch(void* const* d_in, const int* in_sizes, int n_in,
                              void* d_out, int out_size, void* d_ws, size_t ws_size,
                              hipStream_t stream) {
  const float* xs   = (const float*)d_in[0];
  const float* ms   = (const float*)d_in[1];
  const float* h0   = (const float*)d_in[2];
  const float* W_ih = (const float*)d_in[3];
  const float* b_ih = (const float*)d_in[4];
  const float* W_hh = (const float*)d_in[5];
  const float* b_hh = (const float*)d_in[6];
  const float* W_xh = (const float*)d_in[7];
  const float* b_xh = (const float*)d_in[8];
  const float* W_r  = (const float*)d_in[9];
  const float* b_r  = (const float*)d_in[10];

  char* ws = (char*)d_ws;
  size_t off = 0;
  _Float16* xs_h = (_Float16*)(ws + off); off += 67108864;   // [32768][1024] f16
  _Float16* wcat = (_Float16*)(ws + off); off += 8388608;    // [4096][1024] f16
  _Float16* whh  = (_Float16*)(ws + off); off += 6291456;    // [3072][1024] f16
  _Float16* wr   = (_Float16*)(ws + off); off += 2097152;    // [1024][1024] f16
  _Float16* xgh  = (_Float16*)(ws + off); off += 268435456;  // [32768][4096] f16
  _Float16* h_h  = (_Float16*)(ws + off); off += 131072;     // [64][1024] f16
  _Float16* rh_h = (_Float16*)(ws + off); off += 131072;     // [64][1024] f16
  unsigned* bar  = (unsigned*)(ws + off); off += 256;        // barrier counter

  hipMemsetAsync(bar, 0, 256, stream);
  kconv<<<2048, 256, 0, stream>>>(xs, W_ih, W_xh, W_hh, W_r, h0, xs_h, wcat, whh, wr, h_h);
  kgemm<<<dim3(32, 256), 256, 0, stream>>>(xs_h, wcat, b_ih, b_xh, xgh);
  krec<<<64, 256, 0, stream>>>(xgh, ms, whh, wr, b_hh, b_r, h0, h_h, rh_h, (float*)d_out, bar);
}